// Round 7
// baseline (317.084 us; speedup 1.0000x reference)
//
#include <hip/hip_runtime.h>
#include <cstdint>
#include <cstddef>

#define D_MODEL 1024
#define N_HEADS 16
#define HEAD_DIM 64
#define SEQ 2048
#define BATCH 2

typedef __attribute__((ext_vector_type(8))) short bf16x8;
typedef __attribute__((ext_vector_type(4))) float f32x4;

__device__ inline unsigned short f2bf(float f) {
    union { float f; unsigned u; } v; v.f = f;
    unsigned r = v.u + 0x7fffu + ((v.u >> 16) & 1u);
    return (unsigned short)(r >> 16);
}

// async global->LDS (flash kernel only), 16 B per lane.
__device__ __forceinline__ void gload_lds16(const unsigned short* g, unsigned short* l) {
    __builtin_amdgcn_global_load_lds(
        (const __attribute__((address_space(1))) unsigned int*)g,
        (__attribute__((address_space(3))) unsigned int*)l, 16, 0, 0);
}

// ---------------------------------------------------------------------------
// fp32 -> bf16 straight convert (x). 8 floats/thread.
// ---------------------------------------------------------------------------
__global__ __launch_bounds__(256) void convert_x_kernel(
    const float* __restrict__ X, unsigned short* __restrict__ Xb)
{
    const int idx = blockIdx.x * 256 + threadIdx.x;
    const float4* src = (const float4*)X;
    float4 v0 = src[idx * 2], v1 = src[idx * 2 + 1];
    union { unsigned short u[8]; uint4 v; } o;
    o.u[0] = f2bf(v0.x); o.u[1] = f2bf(v0.y); o.u[2] = f2bf(v0.z); o.u[3] = f2bf(v0.w);
    o.u[4] = f2bf(v1.x); o.u[5] = f2bf(v1.y); o.u[6] = f2bf(v1.z); o.u[7] = f2bf(v1.w);
    ((uint4*)Xb)[idx] = o.v;
}

// ---------------------------------------------------------------------------
// w_qkv[k][c] fp32 -> Wqt[n'][k] bf16, PERMUTED: n' = (c%3)*1024 + c/3.
// ---------------------------------------------------------------------------
__global__ __launch_bounds__(256) void convert_transpose_qkv(
    const float* __restrict__ W, unsigned short* __restrict__ Wt)
{
    __shared__ float t[32][33];
    const int c0 = blockIdx.x * 32, r0 = blockIdx.y * 32;
    const int a = threadIdx.x & 31, b = threadIdx.x >> 5;
#pragma unroll
    for (int i = 0; i < 32; i += 8)
        t[b + i][a] = W[(size_t)(r0 + b + i) * (3 * D_MODEL) + c0 + a];
    __syncthreads();
#pragma unroll
    for (int i = 0; i < 32; i += 8) {
        const int c = c0 + b + i;
        const int np = (c % 3) * 1024 + c / 3;
        Wt[(size_t)np * D_MODEL + r0 + a] = f2bf(t[a][b + i]);
    }
}

__global__ __launch_bounds__(256) void convert_transpose_kernel(
    const float* __restrict__ W, unsigned short* __restrict__ Wt,
    int ncols, int nrows)
{
    __shared__ float t[32][33];
    const int c0 = blockIdx.x * 32, r0 = blockIdx.y * 32;
    const int a = threadIdx.x & 31, b = threadIdx.x >> 5;
#pragma unroll
    for (int i = 0; i < 32; i += 8)
        t[b + i][a] = W[(size_t)(r0 + b + i) * ncols + c0 + a];
    __syncthreads();
#pragma unroll
    for (int i = 0; i < 32; i += 8)
        Wt[(size_t)(c0 + b + i) * nrows + r0 + a] = f2bf(t[a][b + i]);
}

// ---------------------------------------------------------------------------
// V[bh][n][d] -> Vt[bh][d][n], 64x64 bf16 tiles through LDS.
// ---------------------------------------------------------------------------
__global__ __launch_bounds__(256) void v_transpose(
    const unsigned short* __restrict__ V, unsigned short* __restrict__ Vt)
{
    const int n0 = blockIdx.x * 64;
    const int bh = blockIdx.y;
    __shared__ unsigned short t[64 * 72];
    const int tid = threadIdx.x;
    const uint4* src = (const uint4*)(V + ((size_t)bh * SEQ + n0) * HEAD_DIM);
#pragma unroll
    for (int it = 0; it < 2; it++) {
        const int lin = tid + it * 256;
        const int row = lin >> 3, p = lin & 7;
        ((uint4*)t)[row * 9 + p] = src[lin];
    }
    __syncthreads();
#pragma unroll
    for (int it = 0; it < 2; it++) {
        const int lin = tid + it * 256;
        const int drow = lin >> 3, p = lin & 7;
        union { unsigned short u[8]; uint4 v; } o;
#pragma unroll
        for (int e = 0; e < 8; e++) o.u[e] = t[(p * 8 + e) * 72 + drow];
        ((uint4*)(Vt + ((size_t)bh * HEAD_DIM + drow) * SEQ + n0))[p] = o.v;
    }
}

// ---------------------------------------------------------------------------
// Pipelined bf16 MFMA GEMM core v4: 128x128 tile, BK=32, REGISTER pipeline
// depth 2 + raw s_barrier (no vmcnt drain). Loads for tile kt+2 issue at
// iter kt and are vmcnt-waited only at the ds_write in iter kt+1 (compiler's
// fine-grained vmcnt(N)) -> ~2 compute phases in flight across barriers.
// LDS: 2 x (8K + 8K) = 32 KB. Frag-order layout (conflict-free b128).
// Barrier discipline: every wave does s_waitcnt lgkmcnt(0); s_barrier between
// write(sb^1)/read(sb) phases — LDS producer/consumer safe; global loads
// deliberately remain outstanding across the barrier.
// ---------------------------------------------------------------------------
#define GBAR() asm volatile("s_waitcnt lgkmcnt(0)\n\ts_barrier" ::: "memory")

#define P_LOAD(d, ktile)                                                       \
    _Pragma("unroll") for (int i = 0; i < 2; i++) {                            \
        a_p[d][i] = *(const uint4*)(Arow[i] + (ktile) * 32);                   \
        b_p[d][i] = *(const uint4*)(Brow[i] + (ktile) * 32);                   \
    }

#define P_WRITE(d, sb)                                                        \
    _Pragma("unroll") for (int i = 0; i < 2; i++) {                            \
        *(uint4*)&As[sb][(w * 2 + i) * 512 + lane * 8] = a_p[d][i];            \
        *(uint4*)&Bs[sb][(w * 2 + i) * 512 + lane * 8] = b_p[d][i];            \
    }

#define P_COMPUTE(sb)                                                         \
    {   bf16x8 af[4], bfr[4];                                                  \
        _Pragma("unroll") for (int i = 0; i < 4; i++)                          \
            af[i] = *(const bf16x8*)&As[sb][(wr * 4 + i) * 512 + lane * 8];    \
        _Pragma("unroll") for (int j = 0; j < 4; j++)                          \
            bfr[j] = *(const bf16x8*)&Bs[sb][(wc * 4 + j) * 512 + lane * 8];   \
        _Pragma("unroll") for (int i = 0; i < 4; i++)                          \
            _Pragma("unroll") for (int j = 0; j < 4; j++)                      \
                acc[i][j] = __builtin_amdgcn_mfma_f32_16x16x32_bf16(           \
                    af[i], bfr[j], acc[i][j], 0, 0, 0);                        \
    }

#define GEMM_PIPE_BODY(A_, B_)                                                 \
    const int tid = threadIdx.x;                                               \
    const int w = tid >> 6, lane = tid & 63;                                   \
    const int l15 = lane & 15, quad = lane >> 4;                               \
    const int wr = w >> 1, wc = w & 1;                                         \
    const int row0 = blockIdx.y * 128, col0 = blockIdx.x * 128;                \
    __shared__ unsigned short As[2][4096];                                     \
    __shared__ unsigned short Bs[2][4096];                                     \
    const f32x4 zero4 = {0.f, 0.f, 0.f, 0.f};                                  \
    f32x4 acc[4][4];                                                           \
    _Pragma("unroll") for (int i = 0; i < 4; i++)                              \
        _Pragma("unroll") for (int j = 0; j < 4; j++) acc[i][j] = zero4;       \
    uint4 a_p[2][2], b_p[2][2];                                                \
    const unsigned short* Arow[2];                                             \
    const unsigned short* Brow[2];                                             \
    _Pragma("unroll") for (int i = 0; i < 2; i++) {                            \
        Arow[i] = (A_) + (size_t)(row0 + (w * 2 + i) * 16 + l15) * 1024 + quad * 8; \
        Brow[i] = (B_) + (size_t)(col0 + (w * 2 + i) * 16 + l15) * 1024 + quad * 8; \
    }                                                                          \
    P_LOAD(0, 0)                                                               \
    P_LOAD(1, 1)                                                               \
    P_WRITE(0, 0)                                                              \
    GBAR();                                                                    \
    _Pragma("unroll 1") for (int kt = 0; kt < 32; kt += 2) {                   \
        if (kt + 2 < 32) { P_LOAD(0, kt + 2) }                                 \
        P_COMPUTE(0)                                                           \
        P_WRITE(1, 1)                                                          \
        GBAR();                                                                \
        if (kt + 3 < 32) { P_LOAD(1, kt + 3) }                                 \
        P_COMPUTE(1)                                                           \
        if (kt + 2 < 32) { P_WRITE(0, 0) }                                     \
        GBAR();                                                                \
    }

// GEMM1: Xb[4096][1024] @ Wqt[3072 perm][1024]^T -> Q/K/V bf16 (coalesced,
// `which` wave-uniform thanks to the permuted weight layout).
__global__ __launch_bounds__(256) void gemm_qkv_mfma(
    const unsigned short* __restrict__ A, const unsigned short* __restrict__ B,
    unsigned short* __restrict__ Q, unsigned short* __restrict__ Kq,
    unsigned short* __restrict__ Vb)
{
    GEMM_PIPE_BODY(A, B)
    const int nbase = col0 + wc * 64;              // wave-uniform
    const int which = nbase >> 10;
    unsigned short* const dst = (which == 0) ? Q : (which == 1) ? Kq : Vb;
#pragma unroll
    for (int i = 0; i < 4; i++) {
#pragma unroll
        for (int r = 0; r < 4; r++) {
            const int row = row0 + wr * 64 + i * 16 + quad * 4 + r;
            const int bb = row >> 11, n = row & (SEQ - 1);
#pragma unroll
            for (int j = 0; j < 4; j++) {
                const int idx = (nbase + j * 16 + l15) & 1023;  // h*64+d
                const int h = idx >> 6, dd = idx & 63;
                dst[(((size_t)(bb * N_HEADS + h)) * SEQ + n) * HEAD_DIM + dd] =
                    f2bf(acc[i][j][r]);
            }
        }
    }
}

// GEMM2: Ob[4096][1024] @ Wpt[1024][1024]^T -> out fp32.
__global__ __launch_bounds__(256) void gemm_proj_mfma(
    const unsigned short* __restrict__ A, const unsigned short* __restrict__ B,
    float* __restrict__ C)
{
    GEMM_PIPE_BODY(A, B)
#pragma unroll
    for (int i = 0; i < 4; i++) {
#pragma unroll
        for (int r = 0; r < 4; r++) {
            const int row = row0 + wr * 64 + i * 16 + quad * 4 + r;
#pragma unroll
            for (int j = 0; j < 4; j++) {
                const int c = col0 + wc * 64 + j * 16 + l15;
                C[(size_t)row * D_MODEL + c] = acc[i][j][r];
            }
        }
    }
}

// ---------------------------------------------------------------------------
// Flash attention (unchanged from R4-R6): S^T trick + register Q + async
// double-buffered K/V staging via global_load_lds + __syncthreads.
// ---------------------------------------------------------------------------
#define PSTR 72

__global__ __launch_bounds__(256) void flash_attn_kernel(
    const unsigned short* __restrict__ Q,
    const unsigned short* __restrict__ K,
    const unsigned short* __restrict__ Vt,
    unsigned short* __restrict__ O)
{
    const int idx = blockIdx.x;
    const int bh = idx & 31;
    const int qt2 = idx >> 5;
    const int hi = qt2 >> 3, lo = qt2 & 7;
    const int qt = (hi == 0) ? lo : (hi == 1) ? 31 - lo : (hi == 2) ? lo + 8 : 23 - lo;

    const int tid = threadIdx.x;
    const int w = tid >> 6, lane = tid & 63;
    const int l15 = lane & 15, quad = lane >> 4;

    __shared__ unsigned short Ks[2][4096];
    __shared__ unsigned short Vs[2][4096];
    __shared__ unsigned short Ps[4][16 * PSTR];

    bf16x8 qf[2];
    {
        const unsigned short* qrow =
            Q + ((size_t)bh * SEQ + qt * 64 + w * 16 + l15) * HEAD_DIM;
        qf[0] = *(const bf16x8*)(qrow + quad * 8);
        qf[1] = *(const bf16x8*)(qrow + 32 + quad * 8);
    }

    const f32x4 zero4 = {0.f, 0.f, 0.f, 0.f};
    f32x4 o_acc[4] = {zero4, zero4, zero4, zero4};
    float m_i = -1e30f, l_i = 0.f;

    auto stage = [&](int bf, int kt_t) {
        const int key0 = kt_t * 64;
#pragma unroll
        for (int i = 0; i < 2; i++) {
            const int f = w * 2 + i;
            const int ct = f >> 1, kh = f & 1;
            gload_lds16(K + ((size_t)bh * SEQ + key0 + ct * 16 + l15) * HEAD_DIM
                          + kh * 32 + quad * 8,
                        &Ks[bf][f * 512 + lane * 8]);
            gload_lds16(Vt + ((size_t)bh * HEAD_DIM + ct * 16 + l15) * SEQ
                           + key0 + kh * 32 + quad * 8,
                        &Vs[bf][f * 512 + lane * 8]);
        }
    };

    stage(0, 0);
    int buf = 0;

    const int qg = qt * 64 + w * 16 + l15;

    for (int kt = 0; kt <= qt; kt++) {
        __syncthreads();
        if (kt < qt) stage(buf ^ 1, kt + 1);

        f32x4 st[4] = {zero4, zero4, zero4, zero4};
#pragma unroll
        for (int kh = 0; kh < 2; kh++) {
#pragma unroll
            for (int ct = 0; ct < 4; ct++) {
                bf16x8 kf = *(const bf16x8*)&Ks[buf][(ct * 2 + kh) * 512 + lane * 8];
                st[ct] = __builtin_amdgcn_mfma_f32_16x16x32_bf16(kf, qf[kh], st[ct], 0, 0, 0);
            }
        }

        const bool diag = (kt == qt);
        float mt = -1e30f;
#pragma unroll
        for (int ct = 0; ct < 4; ct++) {
#pragma unroll
            for (int r = 0; r < 4; r++) {
                float v = st[ct][r] * 0.125f;
                const int kg = kt * 64 + ct * 16 + quad * 4 + r;
                if (diag && kg > qg) v = -1e30f;
                st[ct][r] = v;
                mt = fmaxf(mt, v);
            }
        }
        mt = fmaxf(mt, __shfl_xor(mt, 16));
        mt = fmaxf(mt, __shfl_xor(mt, 32));

        const float mn = fmaxf(m_i, mt);
        const float alpha = __expf(m_i - mn);
        m_i = mn;

        float ls = 0.f;
#pragma unroll
        for (int ct = 0; ct < 4; ct++) {
            union { unsigned short u[4]; uint2 v; } pk;
#pragma unroll
            for (int r = 0; r < 4; r++) {
                float p = __expf(st[ct][r] - mn);
                ls += p;
                pk.u[r] = f2bf(p);
            }
            *(uint2*)&Ps[w][l15 * PSTR + ct * 16 + quad * 4] = pk.v;
        }
        ls += __shfl_xor(ls, 16);
        ls += __shfl_xor(ls, 32);
        l_i = l_i * alpha + ls;

        float ar[4];
#pragma unroll
        for (int r = 0; r < 4; r++)
            ar[r] = __shfl(alpha, (lane & 48) | (quad * 4 + r));
#pragma unroll
        for (int dt = 0; dt < 4; dt++)
#pragma unroll
            for (int r = 0; r < 4; r++)
                o_acc[dt][r] *= ar[r];

#pragma unroll
        for (int kh = 0; kh < 2; kh++) {
            bf16x8 pa = *(const bf16x8*)&Ps[w][l15 * PSTR + kh * 32 + quad * 8];
#pragma unroll
            for (int dt = 0; dt < 4; dt++) {
                bf16x8 vf = *(const bf16x8*)&Vs[buf][(dt * 2 + kh) * 512 + lane * 8];
                o_acc[dt] = __builtin_amdgcn_mfma_f32_16x16x32_bf16(pa, vf, o_acc[dt], 0, 0, 0);
            }
        }
        buf ^= 1;
    }

    const float linv = 1.0f / l_i;
    float lr[4];
#pragma unroll
    for (int r = 0; r < 4; r++)
        lr[r] = __shfl(linv, (lane & 48) | (quad * 4 + r));

    const int b = bh >> 4, h = bh & 15;
#pragma unroll
    for (int r = 0; r < 4; r++) {
        const int q = qt * 64 + w * 16 + quad * 4 + r;
        unsigned short* orow = O + ((size_t)b * SEQ + q) * D_MODEL + h * HEAD_DIM;
#pragma unroll
        for (int dt = 0; dt < 4; dt++)
            orow[dt * 16 + l15] = f2bf(o_acc[dt][r] * lr[r]);
    }
}

// ---------------------------------------------------------------------------
extern "C" void kernel_launch(void* const* d_in, const int* in_sizes, int n_in,
                              void* d_out, int out_size, void* d_ws, size_t ws_size,
                              hipStream_t stream) {
    const float* x      = (const float*)d_in[0];
    const float* w_qkv  = (const float*)d_in[1];
    const float* w_proj = (const float*)d_in[2];
    float* out = (float*)d_out;

    unsigned short* Xb  = (unsigned short*)d_ws;          // 4M shorts
    unsigned short* Wqt = Xb  + (size_t)4 * 1024 * 1024;  // 3M
    unsigned short* Wpt = Wqt + (size_t)3 * 1024 * 1024;  // 1M
    unsigned short* Qb  = Wpt + (size_t)1 * 1024 * 1024;  // 4M
    unsigned short* Kb  = Qb  + (size_t)4 * 1024 * 1024;  // 4M
    unsigned short* Vb  = Kb  + (size_t)4 * 1024 * 1024;  // 4M (untransposed)
    unsigned short* Vtb = Vb  + (size_t)4 * 1024 * 1024;  // 4M
    unsigned short* Ob  = Vtb + (size_t)4 * 1024 * 1024;  // 4M  (56 MB total)

    convert_x_kernel<<<dim3(2048), 256, 0, stream>>>(x, Xb);
    convert_transpose_qkv<<<dim3(3072 / 32, 1024 / 32), 256, 0, stream>>>(w_qkv, Wqt);
    convert_transpose_kernel<<<dim3(1024 / 32, 1024 / 32), 256, 0, stream>>>(
        w_proj, Wpt, D_MODEL, D_MODEL);

    gemm_qkv_mfma<<<dim3(3 * D_MODEL / 128, BATCH * SEQ / 128), 256, 0, stream>>>(
        Xb, Wqt, Qb, Kb, Vb);

    v_transpose<<<dim3(SEQ / 64, BATCH * N_HEADS), 256, 0, stream>>>(Vb, Vtb);

    flash_attn_kernel<<<dim3(SEQ / 64 * BATCH * N_HEADS), 256, 0, stream>>>(
        Qb, Kb, Vtb, Ob);

    gemm_proj_mfma<<<dim3(D_MODEL / 128, BATCH * SEQ / 128), 256, 0, stream>>>(
        Ob, Wpt, out);
}

// Round 8
// 239.019 us; speedup vs baseline: 1.3266x; 1.3266x over previous
//
#include <hip/hip_runtime.h>
#include <cstdint>
#include <cstddef>

#define D_MODEL 1024
#define N_HEADS 16
#define HEAD_DIM 64
#define SEQ 2048
#define BATCH 2

typedef __attribute__((ext_vector_type(8))) short bf16x8;
typedef __attribute__((ext_vector_type(4))) float f32x4;

__device__ inline unsigned short f2bf(float f) {
    union { float f; unsigned u; } v; v.f = f;
    unsigned r = v.u + 0x7fffu + ((v.u >> 16) & 1u);
    return (unsigned short)(r >> 16);
}

// async global->LDS, 16 B per lane; LDS dst must be wave-base + lane*16.
__device__ __forceinline__ void gload_lds16(const unsigned short* g, unsigned short* l) {
    __builtin_amdgcn_global_load_lds(
        (const __attribute__((address_space(1))) unsigned int*)g,
        (__attribute__((address_space(3))) unsigned int*)l, 16, 0, 0);
}

// ---------------------------------------------------------------------------
// fp32 -> bf16 straight convert (x). 8 floats/thread.
// ---------------------------------------------------------------------------
__global__ __launch_bounds__(256) void convert_x_kernel(
    const float* __restrict__ X, unsigned short* __restrict__ Xb)
{
    const int idx = blockIdx.x * 256 + threadIdx.x;
    const float4* src = (const float4*)X;
    float4 v0 = src[idx * 2], v1 = src[idx * 2 + 1];
    union { unsigned short u[8]; uint4 v; } o;
    o.u[0] = f2bf(v0.x); o.u[1] = f2bf(v0.y); o.u[2] = f2bf(v0.z); o.u[3] = f2bf(v0.w);
    o.u[4] = f2bf(v1.x); o.u[5] = f2bf(v1.y); o.u[6] = f2bf(v1.z); o.u[7] = f2bf(v1.w);
    ((uint4*)Xb)[idx] = o.v;
}

// ---------------------------------------------------------------------------
// w_qkv[k][c] fp32 -> Wqt[n'][k] bf16, PERMUTED: n' = (c%3)*1024 + c/3.
// ---------------------------------------------------------------------------
__global__ __launch_bounds__(256) void convert_transpose_qkv(
    const float* __restrict__ W, unsigned short* __restrict__ Wt)
{
    __shared__ float t[32][33];
    const int c0 = blockIdx.x * 32, r0 = blockIdx.y * 32;
    const int a = threadIdx.x & 31, b = threadIdx.x >> 5;
#pragma unroll
    for (int i = 0; i < 32; i += 8)
        t[b + i][a] = W[(size_t)(r0 + b + i) * (3 * D_MODEL) + c0 + a];
    __syncthreads();
#pragma unroll
    for (int i = 0; i < 32; i += 8) {
        const int c = c0 + b + i;
        const int np = (c % 3) * 1024 + c / 3;
        Wt[(size_t)np * D_MODEL + r0 + a] = f2bf(t[a][b + i]);
    }
}

__global__ __launch_bounds__(256) void convert_transpose_kernel(
    const float* __restrict__ W, unsigned short* __restrict__ Wt,
    int ncols, int nrows)
{
    __shared__ float t[32][33];
    const int c0 = blockIdx.x * 32, r0 = blockIdx.y * 32;
    const int a = threadIdx.x & 31, b = threadIdx.x >> 5;
#pragma unroll
    for (int i = 0; i < 32; i += 8)
        t[b + i][a] = W[(size_t)(r0 + b + i) * ncols + c0 + a];
    __syncthreads();
#pragma unroll
    for (int i = 0; i < 32; i += 8)
        Wt[(size_t)(c0 + b + i) * nrows + r0 + a] = f2bf(t[a][b + i]);
}

// ---------------------------------------------------------------------------
// V[bh][n][d] -> Vt[bh][d][n], 64x64 bf16 tiles through LDS.
// ---------------------------------------------------------------------------
__global__ __launch_bounds__(256) void v_transpose(
    const unsigned short* __restrict__ V, unsigned short* __restrict__ Vt)
{
    const int n0 = blockIdx.x * 64;
    const int bh = blockIdx.y;
    __shared__ unsigned short t[64 * 72];
    const int tid = threadIdx.x;
    const uint4* src = (const uint4*)(V + ((size_t)bh * SEQ + n0) * HEAD_DIM);
#pragma unroll
    for (int it = 0; it < 2; it++) {
        const int lin = tid + it * 256;
        const int row = lin >> 3, p = lin & 7;
        ((uint4*)t)[row * 9 + p] = src[lin];
    }
    __syncthreads();
#pragma unroll
    for (int it = 0; it < 2; it++) {
        const int lin = tid + it * 256;
        const int drow = lin >> 3, p = lin & 7;
        union { unsigned short u[8]; uint4 v; } o;
#pragma unroll
        for (int e = 0; e < 8; e++) o.u[e] = t[(p * 8 + e) * 72 + drow];
        ((uint4*)(Vt + ((size_t)bh * HEAD_DIM + drow) * SEQ + n0))[p] = o.v;
    }
}

// ---------------------------------------------------------------------------
// GEMM1 v5: 128x256 tile, 512 threads (8 waves), BK=32, async dbuf
// (R6-proven __syncthreads structure, no inline asm).
// Grid = 12 x 32 = 384 blocks -> ALL resident (2 blocks/CU, 48 KB LDS each).
// Wave w: rows (w>>2)*64, cols (w&3)*64. Staging: 24 frag-loads (A:8, B:16),
// 3 per wave. Frag-order LDS, conflict-free b128 reads.
// ---------------------------------------------------------------------------
__global__ __launch_bounds__(512) void gemm_qkv_mfma(
    const unsigned short* __restrict__ A, const unsigned short* __restrict__ B,
    unsigned short* __restrict__ Q, unsigned short* __restrict__ Kq,
    unsigned short* __restrict__ Vb)
{
    const int tid = threadIdx.x;
    const int w = tid >> 6, lane = tid & 63;
    const int l15 = lane & 15, quad = lane >> 4;
    const int wr = w >> 2, wc = w & 3;
    const int row0 = blockIdx.y * 128, col0 = blockIdx.x * 256;

    __shared__ unsigned short As[2][4096];   // 128 x 32
    __shared__ unsigned short Bs[2][8192];   // 256 x 32

    const f32x4 zero4 = {0.f, 0.f, 0.f, 0.f};
    f32x4 acc[4][4];
#pragma unroll
    for (int i = 0; i < 4; i++)
#pragma unroll
        for (int j = 0; j < 4; j++) acc[i][j] = zero4;

    auto stage_ = [&](int sb, int k0) {
#pragma unroll
        for (int i = 0; i < 3; i++) {
            const int f = w * 3 + i;          // 0..23
            if (f < 8) {
                gload_lds16(A + (size_t)(row0 + f * 16 + l15) * D_MODEL + k0 + quad * 8,
                            &As[sb][f * 512 + lane * 8]);
            } else {
                const int fn = f - 8;         // 0..15
                gload_lds16(B + (size_t)(col0 + fn * 16 + l15) * D_MODEL + k0 + quad * 8,
                            &Bs[sb][fn * 512 + lane * 8]);
            }
        }
    };

    stage_(0, 0);
    for (int kt = 0; kt < 32; kt++) {
        const int sb = kt & 1;
        __syncthreads();
        if (kt + 1 < 32) stage_(sb ^ 1, (kt + 1) * 32);
        bf16x8 af[4], bfr[4];
#pragma unroll
        for (int i = 0; i < 4; i++)
            af[i] = *(const bf16x8*)&As[sb][(wr * 4 + i) * 512 + lane * 8];
#pragma unroll
        for (int j = 0; j < 4; j++)
            bfr[j] = *(const bf16x8*)&Bs[sb][(wc * 4 + j) * 512 + lane * 8];
#pragma unroll
        for (int i = 0; i < 4; i++)
#pragma unroll
            for (int j = 0; j < 4; j++)
                acc[i][j] = __builtin_amdgcn_mfma_f32_16x16x32_bf16(
                    af[i], bfr[j], acc[i][j], 0, 0, 0);
    }

    // epilogue: permuted-N scatter, `which` wave-uniform.
    const int nbase = col0 + wc * 64;
    const int which = nbase >> 10;
    unsigned short* const dst = (which == 0) ? Q : (which == 1) ? Kq : Vb;
#pragma unroll
    for (int i = 0; i < 4; i++) {
#pragma unroll
        for (int r = 0; r < 4; r++) {
            const int row = row0 + wr * 64 + i * 16 + quad * 4 + r;
            const int bb = row >> 11, n = row & (SEQ - 1);
#pragma unroll
            for (int j = 0; j < 4; j++) {
                const int idx = (nbase + j * 16 + l15) & 1023;  // h*64+d
                const int h = idx >> 6, dd = idx & 63;
                dst[(((size_t)(bb * N_HEADS + h)) * SEQ + n) * HEAD_DIM + dd] =
                    f2bf(acc[i][j][r]);
            }
        }
    }
}

// ---------------------------------------------------------------------------
// GEMM2 v5: 128x128 tile, 256 threads, BK=32, async dbuf. 32 KB LDS.
// Grid = 8 x 32 = 256 blocks, all resident.
// ---------------------------------------------------------------------------
__global__ __launch_bounds__(256) void gemm_proj_mfma(
    const unsigned short* __restrict__ A, const unsigned short* __restrict__ B,
    float* __restrict__ C)
{
    const int tid = threadIdx.x;
    const int w = tid >> 6, lane = tid & 63;
    const int l15 = lane & 15, quad = lane >> 4;
    const int wr = w >> 1, wc = w & 1;
    const int row0 = blockIdx.y * 128, col0 = blockIdx.x * 128;

    __shared__ unsigned short As[2][4096];
    __shared__ unsigned short Bs[2][4096];

    const f32x4 zero4 = {0.f, 0.f, 0.f, 0.f};
    f32x4 acc[4][4];
#pragma unroll
    for (int i = 0; i < 4; i++)
#pragma unroll
        for (int j = 0; j < 4; j++) acc[i][j] = zero4;

    auto stage_ = [&](int sb, int k0) {
#pragma unroll
        for (int i = 0; i < 2; i++) {
            const int f = w * 2 + i;
            gload_lds16(A + (size_t)(row0 + f * 16 + l15) * D_MODEL + k0 + quad * 8,
                        &As[sb][f * 512 + lane * 8]);
            gload_lds16(B + (size_t)(col0 + f * 16 + l15) * D_MODEL + k0 + quad * 8,
                        &Bs[sb][f * 512 + lane * 8]);
        }
    };

    stage_(0, 0);
    for (int kt = 0; kt < 32; kt++) {
        const int sb = kt & 1;
        __syncthreads();
        if (kt + 1 < 32) stage_(sb ^ 1, (kt + 1) * 32);
        bf16x8 af[4], bfr[4];
#pragma unroll
        for (int i = 0; i < 4; i++)
            af[i] = *(const bf16x8*)&As[sb][(wr * 4 + i) * 512 + lane * 8];
#pragma unroll
        for (int j = 0; j < 4; j++)
            bfr[j] = *(const bf16x8*)&Bs[sb][(wc * 4 + j) * 512 + lane * 8];
#pragma unroll
        for (int i = 0; i < 4; i++)
#pragma unroll
            for (int j = 0; j < 4; j++)
                acc[i][j] = __builtin_amdgcn_mfma_f32_16x16x32_bf16(
                    af[i], bfr[j], acc[i][j], 0, 0, 0);
    }

#pragma unroll
    for (int i = 0; i < 4; i++) {
#pragma unroll
        for (int r = 0; r < 4; r++) {
            const int row = row0 + wr * 64 + i * 16 + quad * 4 + r;
#pragma unroll
            for (int j = 0; j < 4; j++) {
                const int c = col0 + wc * 64 + j * 16 + l15;
                C[(size_t)row * D_MODEL + c] = acc[i][j][r];
            }
        }
    }
}

// ---------------------------------------------------------------------------
// Flash attention (unchanged from R4-R6): S^T trick + register Q + async
// double-buffered K/V staging.
// ---------------------------------------------------------------------------
#define PSTR 72

__global__ __launch_bounds__(256) void flash_attn_kernel(
    const unsigned short* __restrict__ Q,
    const unsigned short* __restrict__ K,
    const unsigned short* __restrict__ Vt,
    unsigned short* __restrict__ O)
{
    const int idx = blockIdx.x;
    const int bh = idx & 31;
    const int qt2 = idx >> 5;
    const int hi = qt2 >> 3, lo = qt2 & 7;
    const int qt = (hi == 0) ? lo : (hi == 1) ? 31 - lo : (hi == 2) ? lo + 8 : 23 - lo;

    const int tid = threadIdx.x;
    const int w = tid >> 6, lane = tid & 63;
    const int l15 = lane & 15, quad = lane >> 4;

    __shared__ unsigned short Ks[2][4096];
    __shared__ unsigned short Vs[2][4096];
    __shared__ unsigned short Ps[4][16 * PSTR];

    bf16x8 qf[2];
    {
        const unsigned short* qrow =
            Q + ((size_t)bh * SEQ + qt * 64 + w * 16 + l15) * HEAD_DIM;
        qf[0] = *(const bf16x8*)(qrow + quad * 8);
        qf[1] = *(const bf16x8*)(qrow + 32 + quad * 8);
    }

    const f32x4 zero4 = {0.f, 0.f, 0.f, 0.f};
    f32x4 o_acc[4] = {zero4, zero4, zero4, zero4};
    float m_i = -1e30f, l_i = 0.f;

    auto stage = [&](int bf, int kt_t) {
        const int key0 = kt_t * 64;
#pragma unroll
        for (int i = 0; i < 2; i++) {
            const int f = w * 2 + i;
            const int ct = f >> 1, kh = f & 1;
            gload_lds16(K + ((size_t)bh * SEQ + key0 + ct * 16 + l15) * HEAD_DIM
                          + kh * 32 + quad * 8,
                        &Ks[bf][f * 512 + lane * 8]);
            gload_lds16(Vt + ((size_t)bh * HEAD_DIM + ct * 16 + l15) * SEQ
                           + key0 + kh * 32 + quad * 8,
                        &Vs[bf][f * 512 + lane * 8]);
        }
    };

    stage(0, 0);
    int buf = 0;

    const int qg = qt * 64 + w * 16 + l15;

    for (int kt = 0; kt <= qt; kt++) {
        __syncthreads();
        if (kt < qt) stage(buf ^ 1, kt + 1);

        f32x4 st[4] = {zero4, zero4, zero4, zero4};
#pragma unroll
        for (int kh = 0; kh < 2; kh++) {
#pragma unroll
            for (int ct = 0; ct < 4; ct++) {
                bf16x8 kf = *(const bf16x8*)&Ks[buf][(ct * 2 + kh) * 512 + lane * 8];
                st[ct] = __builtin_amdgcn_mfma_f32_16x16x32_bf16(kf, qf[kh], st[ct], 0, 0, 0);
            }
        }

        const bool diag = (kt == qt);
        float mt = -1e30f;
#pragma unroll
        for (int ct = 0; ct < 4; ct++) {
#pragma unroll
            for (int r = 0; r < 4; r++) {
                float v = st[ct][r] * 0.125f;
                const int kg = kt * 64 + ct * 16 + quad * 4 + r;
                if (diag && kg > qg) v = -1e30f;
                st[ct][r] = v;
                mt = fmaxf(mt, v);
            }
        }
        mt = fmaxf(mt, __shfl_xor(mt, 16));
        mt = fmaxf(mt, __shfl_xor(mt, 32));

        const float mn = fmaxf(m_i, mt);
        const float alpha = __expf(m_i - mn);
        m_i = mn;

        float ls = 0.f;
#pragma unroll
        for (int ct = 0; ct < 4; ct++) {
            union { unsigned short u[4]; uint2 v; } pk;
#pragma unroll
            for (int r = 0; r < 4; r++) {
                float p = __expf(st[ct][r] - mn);
                ls += p;
                pk.u[r] = f2bf(p);
            }
            *(uint2*)&Ps[w][l15 * PSTR + ct * 16 + quad * 4] = pk.v;
        }
        ls += __shfl_xor(ls, 16);
        ls += __shfl_xor(ls, 32);
        l_i = l_i * alpha + ls;

        float ar[4];
#pragma unroll
        for (int r = 0; r < 4; r++)
            ar[r] = __shfl(alpha, (lane & 48) | (quad * 4 + r));
#pragma unroll
        for (int dt = 0; dt < 4; dt++)
#pragma unroll
            for (int r = 0; r < 4; r++)
                o_acc[dt][r] *= ar[r];

#pragma unroll
        for (int kh = 0; kh < 2; kh++) {
            bf16x8 pa = *(const bf16x8*)&Ps[w][l15 * PSTR + kh * 32 + quad * 8];
#pragma unroll
            for (int dt = 0; dt < 4; dt++) {
                bf16x8 vf = *(const bf16x8*)&Vs[buf][(dt * 2 + kh) * 512 + lane * 8];
                o_acc[dt] = __builtin_amdgcn_mfma_f32_16x16x32_bf16(pa, vf, o_acc[dt], 0, 0, 0);
            }
        }
        buf ^= 1;
    }

    const float linv = 1.0f / l_i;
    float lr[4];
#pragma unroll
    for (int r = 0; r < 4; r++)
        lr[r] = __shfl(linv, (lane & 48) | (quad * 4 + r));

    const int b = bh >> 4, h = bh & 15;
#pragma unroll
    for (int r = 0; r < 4; r++) {
        const int q = qt * 64 + w * 16 + quad * 4 + r;
        unsigned short* orow = O + ((size_t)b * SEQ + q) * D_MODEL + h * HEAD_DIM;
#pragma unroll
        for (int dt = 0; dt < 4; dt++)
            orow[dt * 16 + l15] = f2bf(o_acc[dt][r] * lr[r]);
    }
}

// ---------------------------------------------------------------------------
extern "C" void kernel_launch(void* const* d_in, const int* in_sizes, int n_in,
                              void* d_out, int out_size, void* d_ws, size_t ws_size,
                              hipStream_t stream) {
    const float* x      = (const float*)d_in[0];
    const float* w_qkv  = (const float*)d_in[1];
    const float* w_proj = (const float*)d_in[2];
    float* out = (float*)d_out;

    unsigned short* Xb  = (unsigned short*)d_ws;          // 4M shorts
    unsigned short* Wqt = Xb  + (size_t)4 * 1024 * 1024;  // 3M
    unsigned short* Wpt = Wqt + (size_t)3 * 1024 * 1024;  // 1M
    unsigned short* Qb  = Wpt + (size_t)1 * 1024 * 1024;  // 4M
    unsigned short* Kb  = Qb  + (size_t)4 * 1024 * 1024;  // 4M
    unsigned short* Vb  = Kb  + (size_t)4 * 1024 * 1024;  // 4M (untransposed)
    unsigned short* Vtb = Vb  + (size_t)4 * 1024 * 1024;  // 4M
    unsigned short* Ob  = Vtb + (size_t)4 * 1024 * 1024;  // 4M  (56 MB total)

    convert_x_kernel<<<dim3(2048), 256, 0, stream>>>(x, Xb);
    convert_transpose_qkv<<<dim3(3072 / 32, 1024 / 32), 256, 0, stream>>>(w_qkv, Wqt);
    convert_transpose_kernel<<<dim3(1024 / 32, 1024 / 32), 256, 0, stream>>>(
        w_proj, Wpt, D_MODEL, D_MODEL);

    gemm_qkv_mfma<<<dim3(3 * D_MODEL / 256, BATCH * SEQ / 128), 512, 0, stream>>>(
        Xb, Wqt, Qb, Kb, Vb);

    v_transpose<<<dim3(SEQ / 64, BATCH * N_HEADS), 256, 0, stream>>>(Vb, Vtb);

    flash_attn_kernel<<<dim3(SEQ / 64 * BATCH * N_HEADS), 256, 0, stream>>>(
        Qb, Kb, Vtb, Ob);

    gemm_proj_mfma<<<dim3(D_MODEL / 128, BATCH * SEQ / 128), 256, 0, stream>>>(
        Ob, Wpt, out);
}

// Round 10
// 234.551 us; speedup vs baseline: 1.3519x; 1.0190x over previous
//
#include <hip/hip_runtime.h>
#include <cstdint>
#include <cstddef>

#define D_MODEL 1024
#define N_HEADS 16
#define HEAD_DIM 64
#define SEQ 2048
#define BATCH 2

typedef __attribute__((ext_vector_type(8))) short bf16x8;
typedef __attribute__((ext_vector_type(4))) float f32x4;

__device__ inline unsigned short f2bf(float f) {
    union { float f; unsigned u; } v; v.f = f;
    unsigned r = v.u + 0x7fffu + ((v.u >> 16) & 1u);
    return (unsigned short)(r >> 16);
}

// async global->LDS, 16 B per lane; LDS dst must be wave-base + lane*16.
__device__ __forceinline__ void gload_lds16(const unsigned short* g, unsigned short* l) {
    __builtin_amdgcn_global_load_lds(
        (const __attribute__((address_space(1))) unsigned int*)g,
        (__attribute__((address_space(3))) unsigned int*)l, 16, 0, 0);
}

// ---------------------------------------------------------------------------
// Fused converts: x->bf16 | w_qkv->Wqt (permuted transpose) | w_proj->Wpt.
//   [0,2048)    : x convert, 8 floats/thread
//   [2048,5120) : qkv permuted transpose, 32x32 tiles (96 x 32)
//   [5120,6144) : proj transpose, 32x32 tiles (32 x 32)
// ---------------------------------------------------------------------------
__global__ __launch_bounds__(256) void fused_convert_kernel(
    const float* __restrict__ X, unsigned short* __restrict__ Xb,
    const float* __restrict__ Wq, unsigned short* __restrict__ Wqt,
    const float* __restrict__ Wp, unsigned short* __restrict__ Wpt)
{
    const int blk = blockIdx.x;
    const int tid = threadIdx.x;
    __shared__ float t[32][33];

    if (blk < 2048) {
        const int idx = blk * 256 + tid;
        const float4* src = (const float4*)X;
        float4 v0 = src[idx * 2], v1 = src[idx * 2 + 1];
        union { unsigned short u[8]; uint4 v; } o;
        o.u[0] = f2bf(v0.x); o.u[1] = f2bf(v0.y); o.u[2] = f2bf(v0.z); o.u[3] = f2bf(v0.w);
        o.u[4] = f2bf(v1.x); o.u[5] = f2bf(v1.y); o.u[6] = f2bf(v1.z); o.u[7] = f2bf(v1.w);
        ((uint4*)Xb)[idx] = o.v;
    } else if (blk < 5120) {
        const int bb = blk - 2048;
        const int c0 = (bb % 96) * 32, r0 = (bb / 96) * 32;
        const int a = tid & 31, b = tid >> 5;
#pragma unroll
        for (int i = 0; i < 32; i += 8)
            t[b + i][a] = Wq[(size_t)(r0 + b + i) * (3 * D_MODEL) + c0 + a];
        __syncthreads();
#pragma unroll
        for (int i = 0; i < 32; i += 8) {
            const int c = c0 + b + i;
            const int np = (c % 3) * 1024 + c / 3;   // which*1024 + h*64 + d
            Wqt[(size_t)np * D_MODEL + r0 + a] = f2bf(t[a][b + i]);
        }
    } else {
        const int bb = blk - 5120;
        const int c0 = (bb % 32) * 32, r0 = (bb / 32) * 32;
        const int a = tid & 31, b = tid >> 5;
#pragma unroll
        for (int i = 0; i < 32; i += 8)
            t[b + i][a] = Wp[(size_t)(r0 + b + i) * D_MODEL + c0 + a];
        __syncthreads();
#pragma unroll
        for (int i = 0; i < 32; i += 8)
            Wpt[(size_t)(c0 + b + i) * D_MODEL + r0 + a] = f2bf(t[a][b + i]);
    }
}

// ---------------------------------------------------------------------------
// V[bh][n][d] -> Vt[bh][d][n], 64x64 bf16 tiles through LDS.
// ---------------------------------------------------------------------------
__global__ __launch_bounds__(256) void v_transpose(
    const unsigned short* __restrict__ V, unsigned short* __restrict__ Vt)
{
    const int n0 = blockIdx.x * 64;
    const int bh = blockIdx.y;
    __shared__ unsigned short t[64 * 72];
    const int tid = threadIdx.x;
    const uint4* src = (const uint4*)(V + ((size_t)bh * SEQ + n0) * HEAD_DIM);
#pragma unroll
    for (int it = 0; it < 2; it++) {
        const int lin = tid + it * 256;
        const int row = lin >> 3, p = lin & 7;
        ((uint4*)t)[row * 9 + p] = src[lin];
    }
    __syncthreads();
#pragma unroll
    for (int it = 0; it < 2; it++) {
        const int lin = tid + it * 256;
        const int drow = lin >> 3, p = lin & 7;
        union { unsigned short u[8]; uint4 v; } o;
#pragma unroll
        for (int e = 0; e < 8; e++) o.u[e] = t[(p * 8 + e) * 72 + drow];
        ((uint4*)(Vt + ((size_t)bh * HEAD_DIM + drow) * SEQ + n0))[p] = o.v;
    }
}

// ---------------------------------------------------------------------------
// GEMM1 (unchanged from R8): 128x256 tile, 512 thr, BK=32, async dbuf.
// Grid 12 x 32 = 384 blocks. Permuted-N epilogue, `which` wave-uniform.
// ---------------------------------------------------------------------------
__global__ __launch_bounds__(512) void gemm_qkv_mfma(
    const unsigned short* __restrict__ A, const unsigned short* __restrict__ B,
    unsigned short* __restrict__ Q, unsigned short* __restrict__ Kq,
    unsigned short* __restrict__ Vb)
{
    const int tid = threadIdx.x;
    const int w = tid >> 6, lane = tid & 63;
    const int l15 = lane & 15, quad = lane >> 4;
    const int wr = w >> 2, wc = w & 3;
    const int row0 = blockIdx.y * 128, col0 = blockIdx.x * 256;

    __shared__ unsigned short As[2][4096];   // 128 x 32
    __shared__ unsigned short Bs[2][8192];   // 256 x 32

    const f32x4 zero4 = {0.f, 0.f, 0.f, 0.f};
    f32x4 acc[4][4];
#pragma unroll
    for (int i = 0; i < 4; i++)
#pragma unroll
        for (int j = 0; j < 4; j++) acc[i][j] = zero4;

    auto stage_ = [&](int sb, int k0) {
#pragma unroll
        for (int i = 0; i < 3; i++) {
            const int f = w * 3 + i;          // 0..23
            if (f < 8) {
                gload_lds16(A + (size_t)(row0 + f * 16 + l15) * D_MODEL + k0 + quad * 8,
                            &As[sb][f * 512 + lane * 8]);
            } else {
                const int fn = f - 8;         // 0..15
                gload_lds16(B + (size_t)(col0 + fn * 16 + l15) * D_MODEL + k0 + quad * 8,
                            &Bs[sb][fn * 512 + lane * 8]);
            }
        }
    };

    stage_(0, 0);
    for (int kt = 0; kt < 32; kt++) {
        const int sb = kt & 1;
        __syncthreads();
        if (kt + 1 < 32) stage_(sb ^ 1, (kt + 1) * 32);
        bf16x8 af[4], bfr[4];
#pragma unroll
        for (int i = 0; i < 4; i++)
            af[i] = *(const bf16x8*)&As[sb][(wr * 4 + i) * 512 + lane * 8];
#pragma unroll
        for (int j = 0; j < 4; j++)
            bfr[j] = *(const bf16x8*)&Bs[sb][(wc * 4 + j) * 512 + lane * 8];
#pragma unroll
        for (int i = 0; i < 4; i++)
#pragma unroll
            for (int j = 0; j < 4; j++)
                acc[i][j] = __builtin_amdgcn_mfma_f32_16x16x32_bf16(
                    af[i], bfr[j], acc[i][j], 0, 0, 0);
    }

    const int nbase = col0 + wc * 64;
    const int which = nbase >> 10;
    unsigned short* const dst = (which == 0) ? Q : (which == 1) ? Kq : Vb;
#pragma unroll
    for (int i = 0; i < 4; i++) {
#pragma unroll
        for (int r = 0; r < 4; r++) {
            const int row = row0 + wr * 64 + i * 16 + quad * 4 + r;
            const int bb = row >> 11, n = row & (SEQ - 1);
#pragma unroll
            for (int j = 0; j < 4; j++) {
                const int idx = (nbase + j * 16 + l15) & 1023;  // h*64+d
                const int h = idx >> 6, dd = idx & 63;
                dst[(((size_t)(bb * N_HEADS + h)) * SEQ + n) * HEAD_DIM + dd] =
                    f2bf(acc[i][j][r]);
            }
        }
    }
}

// ---------------------------------------------------------------------------
// GEMM2: SPLIT-K=2. Grid (8, 32, 2) = 512 blocks -> 2 blocks/CU even,
// 8 waves/CU TLP. Each block: K in [z*512, z*512+512), BK=64 dbuf (8 iters).
// LDS 2*(16K+16K) = 64 KB. Writes fp32 partial to P + z*4M.
// ---------------------------------------------------------------------------
__global__ __launch_bounds__(256) void gemm_proj_splitk(
    const unsigned short* __restrict__ A, const unsigned short* __restrict__ B,
    float* __restrict__ P)
{
    const int tid = threadIdx.x;
    const int w = tid >> 6, lane = tid & 63;
    const int l15 = lane & 15, quad = lane >> 4;
    const int wr = w >> 1, wc = w & 1;
    const int row0 = blockIdx.y * 128, col0 = blockIdx.x * 128;
    const int kbase = blockIdx.z * 512;

    __shared__ unsigned short As[2][8192];   // 128 x 64
    __shared__ unsigned short Bs[2][8192];

    const f32x4 zero4 = {0.f, 0.f, 0.f, 0.f};
    f32x4 acc[4][4];
#pragma unroll
    for (int i = 0; i < 4; i++)
#pragma unroll
        for (int j = 0; j < 4; j++) acc[i][j] = zero4;

    auto stage_ = [&](int sb, int k0) {
#pragma unroll
        for (int i = 0; i < 4; i++) {
            const int fa = w * 4 + i;             // 0..15
            const int mt = fa >> 1, kh = fa & 1;
            const int kc = kbase + k0 + kh * 32 + quad * 8;
            gload_lds16(A + (size_t)(row0 + mt * 16 + l15) * D_MODEL + kc,
                        &As[sb][fa * 512 + lane * 8]);
            gload_lds16(B + (size_t)(col0 + mt * 16 + l15) * D_MODEL + kc,
                        &Bs[sb][fa * 512 + lane * 8]);
        }
    };

    stage_(0, 0);
    for (int kt = 0; kt < 8; kt++) {
        const int sb = kt & 1;
        __syncthreads();
        if (kt + 1 < 8) stage_(sb ^ 1, (kt + 1) * 64);
#pragma unroll
        for (int kh = 0; kh < 2; kh++) {
            bf16x8 af[4], bfr[4];
#pragma unroll
            for (int i = 0; i < 4; i++)
                af[i] = *(const bf16x8*)&As[sb][((wr * 4 + i) * 2 + kh) * 512 + lane * 8];
#pragma unroll
            for (int j = 0; j < 4; j++)
                bfr[j] = *(const bf16x8*)&Bs[sb][((wc * 4 + j) * 2 + kh) * 512 + lane * 8];
#pragma unroll
            for (int i = 0; i < 4; i++)
#pragma unroll
                for (int j = 0; j < 4; j++)
                    acc[i][j] = __builtin_amdgcn_mfma_f32_16x16x32_bf16(
                        af[i], bfr[j], acc[i][j], 0, 0, 0);
        }
    }

    float* const dst = P + (size_t)blockIdx.z * (4096ull * 1024ull);
#pragma unroll
    for (int i = 0; i < 4; i++) {
#pragma unroll
        for (int r = 0; r < 4; r++) {
            const int row = row0 + wr * 64 + i * 16 + quad * 4 + r;
#pragma unroll
            for (int j = 0; j < 4; j++) {
                const int c = col0 + wc * 64 + j * 16 + l15;
                dst[(size_t)row * D_MODEL + c] = acc[i][j][r];
            }
        }
    }
}

// out = P0 + P1 (fp32). out has 4M floats = 1M float4; 1024 blocks x 256 thr
// x 4 float4 each. (R9 bug: grid 4096 wrote 48 MB past d_out -> crash.)
__global__ __launch_bounds__(256) void add_out_kernel(
    const float* __restrict__ P, float* __restrict__ out)
{
    const float4* p0 = (const float4*)P;
    const float4* p1 = (const float4*)(P + 4096ull * 1024ull);
    float4* o = (float4*)out;
    const int base = (blockIdx.x * 256 + threadIdx.x) * 4;
#pragma unroll
    for (int j = 0; j < 4; j++) {
        float4 a = p0[base + j], b = p1[base + j];
        float4 r = {a.x + b.x, a.y + b.y, a.z + b.z, a.w + b.w};
        o[base + j] = r;
    }
}

// ---------------------------------------------------------------------------
// Flash attention (unchanged from R4-R8): S^T trick + register Q + async
// double-buffered K/V staging.
// ---------------------------------------------------------------------------
#define PSTR 72

__global__ __launch_bounds__(256) void flash_attn_kernel(
    const unsigned short* __restrict__ Q,
    const unsigned short* __restrict__ K,
    const unsigned short* __restrict__ Vt,
    unsigned short* __restrict__ O)
{
    const int idx = blockIdx.x;
    const int bh = idx & 31;
    const int qt2 = idx >> 5;
    const int hi = qt2 >> 3, lo = qt2 & 7;
    const int qt = (hi == 0) ? lo : (hi == 1) ? 31 - lo : (hi == 2) ? lo + 8 : 23 - lo;

    const int tid = threadIdx.x;
    const int w = tid >> 6, lane = tid & 63;
    const int l15 = lane & 15, quad = lane >> 4;

    __shared__ unsigned short Ks[2][4096];
    __shared__ unsigned short Vs[2][4096];
    __shared__ unsigned short Ps[4][16 * PSTR];

    bf16x8 qf[2];
    {
        const unsigned short* qrow =
            Q + ((size_t)bh * SEQ + qt * 64 + w * 16 + l15) * HEAD_DIM;
        qf[0] = *(const bf16x8*)(qrow + quad * 8);
        qf[1] = *(const bf16x8*)(qrow + 32 + quad * 8);
    }

    const f32x4 zero4 = {0.f, 0.f, 0.f, 0.f};
    f32x4 o_acc[4] = {zero4, zero4, zero4, zero4};
    float m_i = -1e30f, l_i = 0.f;

    auto stage = [&](int bf, int kt_t) {
        const int key0 = kt_t * 64;
#pragma unroll
        for (int i = 0; i < 2; i++) {
            const int f = w * 2 + i;
            const int ct = f >> 1, kh = f & 1;
            gload_lds16(K + ((size_t)bh * SEQ + key0 + ct * 16 + l15) * HEAD_DIM
                          + kh * 32 + quad * 8,
                        &Ks[bf][f * 512 + lane * 8]);
            gload_lds16(Vt + ((size_t)bh * HEAD_DIM + ct * 16 + l15) * SEQ
                           + key0 + kh * 32 + quad * 8,
                        &Vs[bf][f * 512 + lane * 8]);
        }
    };

    stage(0, 0);
    int buf = 0;

    const int qg = qt * 64 + w * 16 + l15;

    for (int kt = 0; kt <= qt; kt++) {
        __syncthreads();
        if (kt < qt) stage(buf ^ 1, kt + 1);

        f32x4 st[4] = {zero4, zero4, zero4, zero4};
#pragma unroll
        for (int kh = 0; kh < 2; kh++) {
#pragma unroll
            for (int ct = 0; ct < 4; ct++) {
                bf16x8 kf = *(const bf16x8*)&Ks[buf][(ct * 2 + kh) * 512 + lane * 8];
                st[ct] = __builtin_amdgcn_mfma_f32_16x16x32_bf16(kf, qf[kh], st[ct], 0, 0, 0);
            }
        }

        const bool diag = (kt == qt);
        float mt = -1e30f;
#pragma unroll
        for (int ct = 0; ct < 4; ct++) {
#pragma unroll
            for (int r = 0; r < 4; r++) {
                float v = st[ct][r] * 0.125f;
                const int kg = kt * 64 + ct * 16 + quad * 4 + r;
                if (diag && kg > qg) v = -1e30f;
                st[ct][r] = v;
                mt = fmaxf(mt, v);
            }
        }
        mt = fmaxf(mt, __shfl_xor(mt, 16));
        mt = fmaxf(mt, __shfl_xor(mt, 32));

        const float mn = fmaxf(m_i, mt);
        const float alpha = __expf(m_i - mn);
        m_i = mn;

        float ls = 0.f;
#pragma unroll
        for (int ct = 0; ct < 4; ct++) {
            union { unsigned short u[4]; uint2 v; } pk;
#pragma unroll
            for (int r = 0; r < 4; r++) {
                float p = __expf(st[ct][r] - mn);
                ls += p;
                pk.u[r] = f2bf(p);
            }
            *(uint2*)&Ps[w][l15 * PSTR + ct * 16 + quad * 4] = pk.v;
        }
        ls += __shfl_xor(ls, 16);
        ls += __shfl_xor(ls, 32);
        l_i = l_i * alpha + ls;

        float ar[4];
#pragma unroll
        for (int r = 0; r < 4; r++)
            ar[r] = __shfl(alpha, (lane & 48) | (quad * 4 + r));
#pragma unroll
        for (int dt = 0; dt < 4; dt++)
#pragma unroll
            for (int r = 0; r < 4; r++)
                o_acc[dt][r] *= ar[r];

#pragma unroll
        for (int kh = 0; kh < 2; kh++) {
            bf16x8 pa = *(const bf16x8*)&Ps[w][l15 * PSTR + kh * 32 + quad * 8];
#pragma unroll
            for (int dt = 0; dt < 4; dt++) {
                bf16x8 vf = *(const bf16x8*)&Vs[buf][(dt * 2 + kh) * 512 + lane * 8];
                o_acc[dt] = __builtin_amdgcn_mfma_f32_16x16x32_bf16(pa, vf, o_acc[dt], 0, 0, 0);
            }
        }
        buf ^= 1;
    }

    const float linv = 1.0f / l_i;
    float lr[4];
#pragma unroll
    for (int r = 0; r < 4; r++)
        lr[r] = __shfl(linv, (lane & 48) | (quad * 4 + r));

    const int b = bh >> 4, h = bh & 15;
#pragma unroll
    for (int r = 0; r < 4; r++) {
        const int q = qt * 64 + w * 16 + quad * 4 + r;
        unsigned short* orow = O + ((size_t)b * SEQ + q) * D_MODEL + h * HEAD_DIM;
#pragma unroll
        for (int dt = 0; dt < 4; dt++)
            orow[dt * 16 + l15] = f2bf(o_acc[dt][r] * lr[r]);
    }
}

// ---------------------------------------------------------------------------
extern "C" void kernel_launch(void* const* d_in, const int* in_sizes, int n_in,
                              void* d_out, int out_size, void* d_ws, size_t ws_size,
                              hipStream_t stream) {
    const float* x      = (const float*)d_in[0];
    const float* w_qkv  = (const float*)d_in[1];
    const float* w_proj = (const float*)d_in[2];
    float* out = (float*)d_out;

    unsigned short* Xb  = (unsigned short*)d_ws;          // 4M shorts
    unsigned short* Wqt = Xb  + (size_t)4 * 1024 * 1024;  // 3M
    unsigned short* Wpt = Wqt + (size_t)3 * 1024 * 1024;  // 1M
    unsigned short* Qb  = Wpt + (size_t)1 * 1024 * 1024;  // 4M
    unsigned short* Kb  = Qb  + (size_t)4 * 1024 * 1024;  // 4M
    unsigned short* Vb  = Kb  + (size_t)4 * 1024 * 1024;  // 4M (untransposed)
    unsigned short* Vtb = Vb  + (size_t)4 * 1024 * 1024;  // 4M
    unsigned short* Ob  = Vtb + (size_t)4 * 1024 * 1024;  // 4M  (56 MB total)

    // Split-K partials alias Qb..Vtb (32 MB, dead after flash):
    // P0 = Qb..Kb (16 MB), P1 = Vb..Vtb (16 MB), contiguous.
    float* Pp = (float*)Qb;

    fused_convert_kernel<<<dim3(6144), 256, 0, stream>>>(
        x, Xb, w_qkv, Wqt, w_proj, Wpt);

    gemm_qkv_mfma<<<dim3(3 * D_MODEL / 256, BATCH * SEQ / 128), 512, 0, stream>>>(
        Xb, Wqt, Qb, Kb, Vb);

    v_transpose<<<dim3(SEQ / 64, BATCH * N_HEADS), 256, 0, stream>>>(Vb, Vtb);

    flash_attn_kernel<<<dim3(SEQ / 64 * BATCH * N_HEADS), 256, 0, stream>>>(
        Qb, Kb, Vtb, Ob);

    gemm_proj_splitk<<<dim3(D_MODEL / 128, BATCH * SEQ / 128, 2), 256, 0, stream>>>(
        Ob, Wpt, Pp);

    add_out_kernel<<<dim3(1024), 256, 0, stream>>>(Pp, out);
}

// Round 11
// 221.401 us; speedup vs baseline: 1.4322x; 1.0594x over previous
//
#include <hip/hip_runtime.h>
#include <cstdint>
#include <cstddef>

#define D_MODEL 1024
#define N_HEADS 16
#define HEAD_DIM 64
#define SEQ 2048
#define BATCH 2

typedef __attribute__((ext_vector_type(8))) short bf16x8;
typedef __attribute__((ext_vector_type(4))) float f32x4;

__device__ inline unsigned short f2bf(float f) {
    union { float f; unsigned u; } v; v.f = f;
    unsigned r = v.u + 0x7fffu + ((v.u >> 16) & 1u);
    return (unsigned short)(r >> 16);
}

// async global->LDS, 16 B per lane; LDS dst must be wave-base + lane*16.
__device__ __forceinline__ void gload_lds16(const unsigned short* g, unsigned short* l) {
    __builtin_amdgcn_global_load_lds(
        (const __attribute__((address_space(1))) unsigned int*)g,
        (__attribute__((address_space(3))) unsigned int*)l, 16, 0, 0);
}

// s_waitcnt immediates (gfx9 encoding: vmcnt[3:0]|[15:14], expcnt[6:4], lgkmcnt[11:8])
#define WAITCNT_VM4 0x0F74   // vmcnt(4), expcnt/lgkmcnt = no-wait
#define WAITCNT_VM0 0x0F70   // vmcnt(0)

// ---------------------------------------------------------------------------
// Fused converts: x->bf16 | w_qkv->Wqt (permuted transpose) | w_proj->Wpt.
// ---------------------------------------------------------------------------
__global__ __launch_bounds__(256) void fused_convert_kernel(
    const float* __restrict__ X, unsigned short* __restrict__ Xb,
    const float* __restrict__ Wq, unsigned short* __restrict__ Wqt,
    const float* __restrict__ Wp, unsigned short* __restrict__ Wpt)
{
    const int blk = blockIdx.x;
    const int tid = threadIdx.x;
    __shared__ float t[32][33];

    if (blk < 2048) {
        const int idx = blk * 256 + tid;
        const float4* src = (const float4*)X;
        float4 v0 = src[idx * 2], v1 = src[idx * 2 + 1];
        union { unsigned short u[8]; uint4 v; } o;
        o.u[0] = f2bf(v0.x); o.u[1] = f2bf(v0.y); o.u[2] = f2bf(v0.z); o.u[3] = f2bf(v0.w);
        o.u[4] = f2bf(v1.x); o.u[5] = f2bf(v1.y); o.u[6] = f2bf(v1.z); o.u[7] = f2bf(v1.w);
        ((uint4*)Xb)[idx] = o.v;
    } else if (blk < 5120) {
        const int bb = blk - 2048;
        const int c0 = (bb % 96) * 32, r0 = (bb / 96) * 32;
        const int a = tid & 31, b = tid >> 5;
#pragma unroll
        for (int i = 0; i < 32; i += 8)
            t[b + i][a] = Wq[(size_t)(r0 + b + i) * (3 * D_MODEL) + c0 + a];
        __syncthreads();
#pragma unroll
        for (int i = 0; i < 32; i += 8) {
            const int c = c0 + b + i;
            const int np = (c % 3) * 1024 + c / 3;   // which*1024 + h*64 + d
            Wqt[(size_t)np * D_MODEL + r0 + a] = f2bf(t[a][b + i]);
        }
    } else {
        const int bb = blk - 5120;
        const int c0 = (bb % 32) * 32, r0 = (bb / 32) * 32;
        const int a = tid & 31, b = tid >> 5;
#pragma unroll
        for (int i = 0; i < 32; i += 8)
            t[b + i][a] = Wp[(size_t)(r0 + b + i) * D_MODEL + c0 + a];
        __syncthreads();
#pragma unroll
        for (int i = 0; i < 32; i += 8)
            Wpt[(size_t)(c0 + b + i) * D_MODEL + r0 + a] = f2bf(t[a][b + i]);
    }
}

// ---------------------------------------------------------------------------
// V[bh][n][d] -> Vt[bh][d][n], 64x64 bf16 tiles through LDS.
// ---------------------------------------------------------------------------
__global__ __launch_bounds__(256) void v_transpose(
    const unsigned short* __restrict__ V, unsigned short* __restrict__ Vt)
{
    const int n0 = blockIdx.x * 64;
    const int bh = blockIdx.y;
    __shared__ unsigned short t[64 * 72];
    const int tid = threadIdx.x;
    const uint4* src = (const uint4*)(V + ((size_t)bh * SEQ + n0) * HEAD_DIM);
#pragma unroll
    for (int it = 0; it < 2; it++) {
        const int lin = tid + it * 256;
        const int row = lin >> 3, p = lin & 7;
        ((uint4*)t)[row * 9 + p] = src[lin];
    }
    __syncthreads();
#pragma unroll
    for (int it = 0; it < 2; it++) {
        const int lin = tid + it * 256;
        const int drow = lin >> 3, p = lin & 7;
        union { unsigned short u[8]; uint4 v; } o;
#pragma unroll
        for (int e = 0; e < 8; e++) o.u[e] = t[(p * 8 + e) * 72 + drow];
        ((uint4*)(Vt + ((size_t)bh * HEAD_DIM + drow) * SEQ + n0))[p] = o.v;
    }
}

// ---------------------------------------------------------------------------
// Pipelined GEMM core v7: 128x128 tile, 256 thr, BK=32, TRIPLE-buffered LDS,
// stage depth 2, raw s_barrier + explicit vmcnt (builtins, no asm).
// Per iter: waitcnt vmcnt(4) [tile kt drained; kt+1 still in flight] ->
// s_barrier [publish slot kt] -> stage tile kt+2 -> compute slot kt%3.
// Tile kt+2's loads remain in flight ACROSS the next barrier (no vmcnt(0)
// drain per iteration — the structural fix for the m97-style stall).
// LDS 3*(8K+8K) = 48 KB -> 3 blocks/CU. L = 4 loads/wave/tile.
// ---------------------------------------------------------------------------
#define GEMM_PIPE3_BODY(A_, B_, KBASE, NITER)                                  \
    const int tid = threadIdx.x;                                               \
    const int w = tid >> 6, lane = tid & 63;                                   \
    const int l15 = lane & 15, quad = lane >> 4;                               \
    const int wr = w >> 1, wc = w & 1;                                         \
    const int row0 = blockIdx.y * 128, col0 = blockIdx.x * 128;                \
    __shared__ unsigned short As[3][4096];                                     \
    __shared__ unsigned short Bs[3][4096];                                     \
    const f32x4 zero4 = {0.f, 0.f, 0.f, 0.f};                                  \
    f32x4 acc[4][4];                                                           \
    _Pragma("unroll") for (int i = 0; i < 4; i++)                              \
        _Pragma("unroll") for (int j = 0; j < 4; j++) acc[i][j] = zero4;       \
    auto stage_ = [&](int sb, int kt_) {                                       \
        const int k0 = (KBASE) + kt_ * 32 + quad * 8;                          \
        _Pragma("unroll") for (int i = 0; i < 2; i++) {                        \
            const int f = w * 2 + i;                                           \
            gload_lds16((A_) + (size_t)(row0 + f * 16 + l15) * D_MODEL + k0,   \
                        &As[sb][f * 512 + lane * 8]);                          \
            gload_lds16((B_) + (size_t)(col0 + f * 16 + l15) * D_MODEL + k0,   \
                        &Bs[sb][f * 512 + lane * 8]);                          \
        }                                                                      \
    };                                                                         \
    stage_(0, 0);                                                              \
    stage_(1, 1);                                                              \
    int sb = 0;                                                                \
    for (int kt = 0; kt < (NITER); kt++) {                                     \
        if (kt < (NITER) - 1) {                                                \
            __builtin_amdgcn_s_waitcnt(WAITCNT_VM4);                           \
            __builtin_amdgcn_s_barrier();                                      \
            if (kt + 2 < (NITER)) stage_((sb + 2 > 2) ? sb - 1 : sb + 2, kt + 2); \
        } else {                                                               \
            __builtin_amdgcn_s_waitcnt(WAITCNT_VM0);                           \
            __builtin_amdgcn_s_barrier();                                      \
        }                                                                      \
        bf16x8 af[4], bfr[4];                                                  \
        _Pragma("unroll") for (int i = 0; i < 4; i++)                          \
            af[i] = *(const bf16x8*)&As[sb][(wr * 4 + i) * 512 + lane * 8];    \
        _Pragma("unroll") for (int j = 0; j < 4; j++)                          \
            bfr[j] = *(const bf16x8*)&Bs[sb][(wc * 4 + j) * 512 + lane * 8];   \
        _Pragma("unroll") for (int i = 0; i < 4; i++)                          \
            _Pragma("unroll") for (int j = 0; j < 4; j++)                      \
                acc[i][j] = __builtin_amdgcn_mfma_f32_16x16x32_bf16(           \
                    af[i], bfr[j], acc[i][j], 0, 0, 0);                        \
        sb = (sb == 2) ? 0 : sb + 1;                                           \
    }

// GEMM1: Xb[4096][1024] @ Wqt[3072 perm][1024]^T -> Q/K/V bf16.
// Grid (24, 32) = 768 blocks -> 3/CU. Permuted N: which wave-uniform.
__global__ __launch_bounds__(256) void gemm_qkv_mfma(
    const unsigned short* __restrict__ A, const unsigned short* __restrict__ B,
    unsigned short* __restrict__ Q, unsigned short* __restrict__ Kq,
    unsigned short* __restrict__ Vb)
{
    GEMM_PIPE3_BODY(A, B, 0, 32)
    const int nbase = col0 + wc * 64;              // wave-uniform, mult of 64
    const int which = nbase >> 10;
    unsigned short* const dst = (which == 0) ? Q : (which == 1) ? Kq : Vb;
#pragma unroll
    for (int i = 0; i < 4; i++) {
#pragma unroll
        for (int r = 0; r < 4; r++) {
            const int row = row0 + wr * 64 + i * 16 + quad * 4 + r;
            const int bb = row >> 11, n = row & (SEQ - 1);
#pragma unroll
            for (int j = 0; j < 4; j++) {
                const int idx = (nbase + j * 16 + l15) & 1023;  // h*64+d
                const int h = idx >> 6, dd = idx & 63;
                dst[(((size_t)(bb * N_HEADS + h)) * SEQ + n) * HEAD_DIM + dd] =
                    f2bf(acc[i][j][r]);
            }
        }
    }
}

// GEMM2: SPLIT-K=2, pipelined. Grid (8, 32, 2) = 512 blocks. K=512/block,
// NITER=16. Writes fp32 partial to P + z*4M.
__global__ __launch_bounds__(256) void gemm_proj_splitk(
    const unsigned short* __restrict__ A, const unsigned short* __restrict__ B,
    float* __restrict__ P)
{
    const int kbase = blockIdx.z * 512;
    GEMM_PIPE3_BODY(A, B, kbase, 16)
    float* const dst = P + (size_t)blockIdx.z * (4096ull * 1024ull);
#pragma unroll
    for (int i = 0; i < 4; i++) {
#pragma unroll
        for (int r = 0; r < 4; r++) {
            const int row = row0 + wr * 64 + i * 16 + quad * 4 + r;
#pragma unroll
            for (int j = 0; j < 4; j++) {
                const int c = col0 + wc * 64 + j * 16 + l15;
                dst[(size_t)row * D_MODEL + c] = acc[i][j][r];
            }
        }
    }
}

// out = P0 + P1 (fp32). 4M floats = 1M float4; 1024 blocks x 256 thr x 4.
__global__ __launch_bounds__(256) void add_out_kernel(
    const float* __restrict__ P, float* __restrict__ out)
{
    const float4* p0 = (const float4*)P;
    const float4* p1 = (const float4*)(P + 4096ull * 1024ull);
    float4* o = (float4*)out;
    const int base = (blockIdx.x * 256 + threadIdx.x) * 4;
#pragma unroll
    for (int j = 0; j < 4; j++) {
        float4 a = p0[base + j], b = p1[base + j];
        float4 r = {a.x + b.x, a.y + b.y, a.z + b.z, a.w + b.w};
        o[base + j] = r;
    }
}

// ---------------------------------------------------------------------------
// Flash attention (unchanged from R4-R10): S^T trick + register Q + async
// double-buffered K/V staging.
// ---------------------------------------------------------------------------
#define PSTR 72

__global__ __launch_bounds__(256) void flash_attn_kernel(
    const unsigned short* __restrict__ Q,
    const unsigned short* __restrict__ K,
    const unsigned short* __restrict__ Vt,
    unsigned short* __restrict__ O)
{
    const int idx = blockIdx.x;
    const int bh = idx & 31;
    const int qt2 = idx >> 5;
    const int hi = qt2 >> 3, lo = qt2 & 7;
    const int qt = (hi == 0) ? lo : (hi == 1) ? 31 - lo : (hi == 2) ? lo + 8 : 23 - lo;

    const int tid = threadIdx.x;
    const int w = tid >> 6, lane = tid & 63;
    const int l15 = lane & 15, quad = lane >> 4;

    __shared__ unsigned short Ks[2][4096];
    __shared__ unsigned short Vs[2][4096];
    __shared__ unsigned short Ps[4][16 * PSTR];

    bf16x8 qf[2];
    {
        const unsigned short* qrow =
            Q + ((size_t)bh * SEQ + qt * 64 + w * 16 + l15) * HEAD_DIM;
        qf[0] = *(const bf16x8*)(qrow + quad * 8);
        qf[1] = *(const bf16x8*)(qrow + 32 + quad * 8);
    }

    const f32x4 zero4 = {0.f, 0.f, 0.f, 0.f};
    f32x4 o_acc[4] = {zero4, zero4, zero4, zero4};
    float m_i = -1e30f, l_i = 0.f;

    auto stage = [&](int bf, int kt_t) {
        const int key0 = kt_t * 64;
#pragma unroll
        for (int i = 0; i < 2; i++) {
            const int f = w * 2 + i;
            const int ct = f >> 1, kh = f & 1;
            gload_lds16(K + ((size_t)bh * SEQ + key0 + ct * 16 + l15) * HEAD_DIM
                          + kh * 32 + quad * 8,
                        &Ks[bf][f * 512 + lane * 8]);
            gload_lds16(Vt + ((size_t)bh * HEAD_DIM + ct * 16 + l15) * SEQ
                           + key0 + kh * 32 + quad * 8,
                        &Vs[bf][f * 512 + lane * 8]);
        }
    };

    stage(0, 0);
    int buf = 0;

    const int qg = qt * 64 + w * 16 + l15;

    for (int kt = 0; kt <= qt; kt++) {
        __syncthreads();
        if (kt < qt) stage(buf ^ 1, kt + 1);

        f32x4 st[4] = {zero4, zero4, zero4, zero4};
#pragma unroll
        for (int kh = 0; kh < 2; kh++) {
#pragma unroll
            for (int ct = 0; ct < 4; ct++) {
                bf16x8 kf = *(const bf16x8*)&Ks[buf][(ct * 2 + kh) * 512 + lane * 8];
                st[ct] = __builtin_amdgcn_mfma_f32_16x16x32_bf16(kf, qf[kh], st[ct], 0, 0, 0);
            }
        }

        const bool diag = (kt == qt);
        float mt = -1e30f;
#pragma unroll
        for (int ct = 0; ct < 4; ct++) {
#pragma unroll
            for (int r = 0; r < 4; r++) {
                float v = st[ct][r] * 0.125f;
                const int kg = kt * 64 + ct * 16 + quad * 4 + r;
                if (diag && kg > qg) v = -1e30f;
                st[ct][r] = v;
                mt = fmaxf(mt, v);
            }
        }
        mt = fmaxf(mt, __shfl_xor(mt, 16));
        mt = fmaxf(mt, __shfl_xor(mt, 32));

        const float mn = fmaxf(m_i, mt);
        const float alpha = __expf(m_i - mn);
        m_i = mn;

        float ls = 0.f;
#pragma unroll
        for (int ct = 0; ct < 4; ct++) {
            union { unsigned short u[4]; uint2 v; } pk;
#pragma unroll
            for (int r = 0; r < 4; r++) {
                float p = __expf(st[ct][r] - mn);
                ls += p;
                pk.u[r] = f2bf(p);
            }
            *(uint2*)&Ps[w][l15 * PSTR + ct * 16 + quad * 4] = pk.v;
        }
        ls += __shfl_xor(ls, 16);
        ls += __shfl_xor(ls, 32);
        l_i = l_i * alpha + ls;

        float ar[4];
#pragma unroll
        for (int r = 0; r < 4; r++)
            ar[r] = __shfl(alpha, (lane & 48) | (quad * 4 + r));
#pragma unroll
        for (int dt = 0; dt < 4; dt++)
#pragma unroll
            for (int r = 0; r < 4; r++)
                o_acc[dt][r] *= ar[r];

#pragma unroll
        for (int kh = 0; kh < 2; kh++) {
            bf16x8 pa = *(const bf16x8*)&Ps[w][l15 * PSTR + kh * 32 + quad * 8];
#pragma unroll
            for (int dt = 0; dt < 4; dt++) {
                bf16x8 vf = *(const bf16x8*)&Vs[buf][(dt * 2 + kh) * 512 + lane * 8];
                o_acc[dt] = __builtin_amdgcn_mfma_f32_16x16x32_bf16(pa, vf, o_acc[dt], 0, 0, 0);
            }
        }
        buf ^= 1;
    }

    const float linv = 1.0f / l_i;
    float lr[4];
#pragma unroll
    for (int r = 0; r < 4; r++)
        lr[r] = __shfl(linv, (lane & 48) | (quad * 4 + r));

    const int b = bh >> 4, h = bh & 15;
#pragma unroll
    for (int r = 0; r < 4; r++) {
        const int q = qt * 64 + w * 16 + quad * 4 + r;
        unsigned short* orow = O + ((size_t)b * SEQ + q) * D_MODEL + h * HEAD_DIM;
#pragma unroll
        for (int dt = 0; dt < 4; dt++)
            orow[dt * 16 + l15] = f2bf(o_acc[dt][r] * lr[r]);
    }
}

// ---------------------------------------------------------------------------
extern "C" void kernel_launch(void* const* d_in, const int* in_sizes, int n_in,
                              void* d_out, int out_size, void* d_ws, size_t ws_size,
                              hipStream_t stream) {
    const float* x      = (const float*)d_in[0];
    const float* w_qkv  = (const float*)d_in[1];
    const float* w_proj = (const float*)d_in[2];
    float* out = (float*)d_out;

    unsigned short* Xb  = (unsigned short*)d_ws;          // 4M shorts
    unsigned short* Wqt = Xb  + (size_t)4 * 1024 * 1024;  // 3M
    unsigned short* Wpt = Wqt + (size_t)3 * 1024 * 1024;  // 1M
    unsigned short* Qb  = Wpt + (size_t)1 * 1024 * 1024;  // 4M
    unsigned short* Kb  = Qb  + (size_t)4 * 1024 * 1024;  // 4M
    unsigned short* Vb  = Kb  + (size_t)4 * 1024 * 1024;  // 4M (untransposed)
    unsigned short* Vtb = Vb  + (size_t)4 * 1024 * 1024;  // 4M
    unsigned short* Ob  = Vtb + (size_t)4 * 1024 * 1024;  // 4M  (56 MB total)

    // Split-K partials alias Qb..Vtb (32 MB, dead after flash):
    // P0 = Qb..Kb (16 MB), P1 = Vb..Vtb (16 MB), contiguous.
    float* Pp = (float*)Qb;

    fused_convert_kernel<<<dim3(6144), 256, 0, stream>>>(
        x, Xb, w_qkv, Wqt, w_proj, Wpt);

    gemm_qkv_mfma<<<dim3(3 * D_MODEL / 128, BATCH * SEQ / 128), 256, 0, stream>>>(
        Xb, Wqt, Qb, Kb, Vb);

    v_transpose<<<dim3(SEQ / 64, BATCH * N_HEADS), 256, 0, stream>>>(Vb, Vtb);

    flash_attn_kernel<<<dim3(SEQ / 64 * BATCH * N_HEADS), 256, 0, stream>>>(
        Qb, Kb, Vtb, Ob);

    gemm_proj_splitk<<<dim3(D_MODEL / 128, BATCH * SEQ / 128, 2), 256, 0, stream>>>(
        Ob, Wpt, Pp);

    add_out_kernel<<<dim3(1024), 256, 0, stream>>>(Pp, out);
}